// Round 3
// baseline (118.305 us; speedup 1.0000x reference)
//
#include <hip/hip_runtime.h>
#include <hip/hip_bf16.h>

typedef __attribute__((ext_vector_type(8))) short bf16x8;
typedef __attribute__((ext_vector_type(4))) float f32x4;

#define B_N   16384
#define INP_N 4096
#define M_N   100
#define K_N   32
#define HID_N 32
#define OUT_W 10

// ---------------- workspace layout (bytes) ----------------
#define WS_TW1 0u         // bf16[100][32][32]   tW1[m][h][k]      204800
#define WS_TW2 204800u    // bf16[100][16][32]   tW2[m][o(pad)][h] 102400
#define WS_TB1 307200u    // f32 [100][32]       tb1               12800
#define WS_TB2 320000u    // f32 [100][16]       tb2               6400
#define WS_COL 326400u    // u16 [100][32]       idx cols packed   6400
// total 332800 B

// ---------------- kernel-2 LDS layout (bytes) ----------------
#define ROWB   8208                  // bf16 row: 8192 B data + 16 B pad (4-bank rotate/row)
#define BUFB   (8 * ROWB)            // 65664 per tile buffer (8 rows)
#define REDOFF (2 * BUFB)            // 131328: per-wave out partials
#define REDSTR 352                   // 88 f32 per wave (16B aligned, rotates banks)
#define COLOFF (REDOFF + 16 * REDSTR)   // 136960: u16[100][32] col table
#define TB1OFF (COLOFF + 6400)          // 143360: f32[100][32] tb1
#define TB2OFF (TB1OFF + 12800)         // 156160: f32[10] summed tb2
#define LDS_SZ (TB2OFF + 64)            // 156224  (<= 163840)

__device__ __forceinline__ unsigned int pkbf(float a, float b) {
    __hip_bfloat162 h2 = __float22bfloat162_rn(make_float2(a, b));
    unsigned int r;
    __builtin_memcpy(&r, &h2, 4);
    return r;
}

// =====================================================================
// Kernel 1: fused hypernetwork.  One block per m, 512 threads.
// All dots use 4 independent partial sums (break dependent-FMA chain).
// =====================================================================
__global__ __launch_bounds__(512) void hyper_kernel(
    const int* __restrict__ idx,
    const float* __restrict__ Wi, const float* __restrict__ bi,
    const float* __restrict__ W1, const float* __restrict__ b1,
    const float* __restrict__ W2, const float* __restrict__ b2,
    const float* __restrict__ Wo, const float* __restrict__ bo,
    char* __restrict__ ws)
{
    __shared__ int   s_idx[K_N];
    __shared__ float s_h0[64];
    __shared__ float s_h1[256];
    __shared__ float s_h2[128];
    const int m = blockIdx.x;
    const int t = threadIdx.x;

    __hip_bfloat16* tW1bf = (__hip_bfloat16*)(ws + WS_TW1);
    __hip_bfloat16* tW2bf = (__hip_bfloat16*)(ws + WS_TW2);
    float* tb1f = (float*)(ws + WS_TB1);
    float* tb2f = (float*)(ws + WS_TB2);
    unsigned short* colb = (unsigned short*)(ws + WS_COL);

    if (t < K_N) {
        int c = idx[m * K_N + t];
        s_idx[t] = c;
        colb[m * K_N + t] = (unsigned short)c;
    }
    __syncthreads();

    // h0 = relu(mask @ Wi.T + bi): sum over UNIQUE idx columns (idx sorted)
    if (t < 64) {
        float s = bi[t];
        const float* wr = Wi + t * INP_N;
        int prev = -1;
        for (int k = 0; k < K_N; ++k) {
            int c = s_idx[k];
            if (c != prev) s += wr[c];
            prev = c;
        }
        s_h0[t] = fmaxf(s, 0.f);
    }
    __syncthreads();

    if (t < 256) { // h1 = relu(W1 h0 + b1)
        float4 a = {0.f, 0.f, 0.f, 0.f};
        const float4* wr = (const float4*)(W1 + t * 64);
        const float4* h0v = (const float4*)s_h0;
        #pragma unroll
        for (int i = 0; i < 16; ++i) {
            float4 w4 = wr[i], a4 = h0v[i];
            a.x += w4.x * a4.x; a.y += w4.y * a4.y;
            a.z += w4.z * a4.z; a.w += w4.w * a4.w;
        }
        s_h1[t] = fmaxf(b1[t] + (a.x + a.y) + (a.z + a.w), 0.f);
    }
    __syncthreads();

    if (t < 128) { // h2 = relu(W2 h1 + b2)
        float4 a = {0.f, 0.f, 0.f, 0.f};
        const float4* wr = (const float4*)(W2 + t * 256);
        const float4* h1v = (const float4*)s_h1;
        #pragma unroll
        for (int i = 0; i < 64; ++i) {
            float4 w4 = wr[i], a4 = h1v[i];
            a.x += w4.x * a4.x; a.y += w4.y * a4.y;
            a.z += w4.z * a4.z; a.w += w4.w * a4.w;
        }
        s_h2[t] = fmaxf(b2[t] + (a.x + a.y) + (a.z + a.w), 0.f);
    }
    __syncthreads();

    // head: w = Wo h2 + bo (1386 outputs), routed to weight tensors
    for (int o = t; o < 1386; o += 512) {
        float4 a = {0.f, 0.f, 0.f, 0.f};
        const float4* wr = (const float4*)(Wo + o * 128);
        const float4* h2v = (const float4*)s_h2;
        #pragma unroll
        for (int i = 0; i < 32; ++i) {
            float4 w4 = wr[i], a4 = h2v[i];
            a.x += w4.x * a4.x; a.y += w4.y * a4.y;
            a.z += w4.z * a4.z; a.w += w4.w * a4.w;
        }
        float s = bo[o] + (a.x + a.y) + (a.z + a.w);
        if (o < 1024) {                     // tW1[m][h][k], h=o>>5, k=o&31
            tW1bf[m * 1024 + o] = __float2bfloat16(s);
        } else if (o < 1056) {
            tb1f[m * 32 + (o - 1024)] = s;
        } else if (o < 1376) {              // tW2[m][o'][h], o'=i>>5, h=i&31
            tW2bf[m * 512 + (o - 1056)] = __float2bfloat16(s);
        } else {
            tb2f[m * 16 + (o - 1376)] = s;
        }
    }
    // zero padded tW2 rows o'=10..15 (offsets 320..511, disjoint from above)
    if (t < 192) tW2bf[m * 512 + 320 + t] = __float2bfloat16(0.f);
}

// =====================================================================
// Kernel 2: main loop.  256 blocks (1/CU) x 1024 thr (16 waves).
// Per tile & m: MFMA1 = mfma(W1, md) -> C[h][b]; shfl-transpose the
// packed bf16 th across lanes (same ln15) to build MFMA2's B-frag;
// MFMA2 = mfma(W2, th) -> acc[o][b] accumulated over m.  No LDS bounce.
// =====================================================================
__global__ __launch_bounds__(1024, 4) void main_kernel(
    const float* __restrict__ data,
    const char* __restrict__ ws,
    float* __restrict__ out)
{
    extern __shared__ char smem[];
    const int tid  = threadIdx.x;
    const int lane = tid & 63;
    const int wave = tid >> 6;       // 0..15
    const int kg   = lane >> 4;      // 0..3  (MFMA k-group)
    const int ln15 = lane & 15;
    const int srow  = wave >> 1;     // staging: row 0..7
    const int shalf = wave & 1;      // staging: half 0/1

    unsigned int* s_col = (unsigned int*)(smem + COLOFF);
    float* s_tb1 = (float*)(smem + TB1OFF);
    float* tb2s  = (float*)(smem + TB2OFF);

    // ---- prologue: small tables -> LDS, stage tile0 into buf0 ----
    {
        const unsigned int* colg = (const unsigned int*)(ws + WS_COL);
        for (int i = tid; i < 1600; i += 1024) s_col[i] = colg[i];
        const float* tb1g = (const float*)(ws + WS_TB1);
        for (int i = tid; i < 3200; i += 1024) s_tb1[i] = tb1g[i];
        if (tid < OUT_W) {
            const float* tb2f = (const float*)(ws + WS_TB2);
            float s = 0.f;
            for (int mm = 0; mm < M_N; ++mm) s += tb2f[mm * 16 + tid];
            tb2s[tid] = s;
        }
    }

    const int tile0 = blockIdx.x * 8;
    const int mlo = (wave * M_N) >> 4;
    const int mhi = ((wave + 1) * M_N) >> 4;
    const int sA = ln15 + ((kg & 1) << 5);   // shfl-transpose source lanes
    const int sB = sA + 16;
    const bool klow = (kg < 2);

    float4 v[8];                     // staging registers (half row / wave)

    {
        const float* rp = data + (size_t)(tile0 * 8 + srow) * INP_N + shalf * 2048;
        #pragma unroll
        for (int j = 0; j < 4; ++j) {
            v[2 * j]     = *(const float4*)(rp + j * 512 + lane * 8);
            v[2 * j + 1] = *(const float4*)(rp + j * 512 + lane * 8 + 4);
        }
        char* bp = smem + srow * ROWB + shalf * 4096;
        #pragma unroll
        for (int j = 0; j < 4; ++j) {
            uint4 pk;
            pk.x = pkbf(v[2 * j].x,     v[2 * j].y);
            pk.y = pkbf(v[2 * j].z,     v[2 * j].w);
            pk.z = pkbf(v[2 * j + 1].x, v[2 * j + 1].y);
            pk.w = pkbf(v[2 * j + 1].z, v[2 * j + 1].w);
            *(uint4*)(bp + j * 1024 + lane * 16) = pk;
        }
    }
    __syncthreads();

    for (int ti = 0; ti < 8; ++ti) {
        const int cur = ti & 1;
        // issue next-tile global loads EARLY (hide HBM under compute)
        if (ti < 7) {
            const float* rp = data + (size_t)((tile0 + ti + 1) * 8 + srow) * INP_N + shalf * 2048;
            #pragma unroll
            for (int j = 0; j < 4; ++j) {
                v[2 * j]     = *(const float4*)(rp + j * 512 + lane * 8);
                v[2 * j + 1] = *(const float4*)(rp + j * 512 + lane * 8 + 4);
            }
        }

        // ---- compute current tile ----
        const char* gbase = smem + cur * BUFB + (ln15 & 7) * ROWB;
        f32x4 acc = {0.f, 0.f, 0.f, 0.f};

        for (int m = mlo; m < mhi; ++m) {
            // B-frag (md): md[b=ln15][k=kg*8+j] gathered from staged bf16 row
            const uint4 cw = *(const uint4*)((const char*)s_col + m * 64 + kg * 16);
            unsigned short u0 = *(const unsigned short*)(gbase + 2 * (cw.x & 0xFFFFu));
            unsigned short u1 = *(const unsigned short*)(gbase + 2 * (cw.x >> 16));
            unsigned short u2 = *(const unsigned short*)(gbase + 2 * (cw.y & 0xFFFFu));
            unsigned short u3 = *(const unsigned short*)(gbase + 2 * (cw.y >> 16));
            unsigned short u4 = *(const unsigned short*)(gbase + 2 * (cw.z & 0xFFFFu));
            unsigned short u5 = *(const unsigned short*)(gbase + 2 * (cw.z >> 16));
            unsigned short u6 = *(const unsigned short*)(gbase + 2 * (cw.w & 0xFFFFu));
            unsigned short u7 = *(const unsigned short*)(gbase + 2 * (cw.w >> 16));
            union { unsigned int ui[4]; bf16x8 v8; } af;
            af.ui[0] = (unsigned int)u0 | ((unsigned int)u1 << 16);
            af.ui[1] = (unsigned int)u2 | ((unsigned int)u3 << 16);
            af.ui[2] = (unsigned int)u4 | ((unsigned int)u5 << 16);
            af.ui[3] = (unsigned int)u6 | ((unsigned int)u7 << 16);

            // A-frags: tW1 rows h=ln15 / h=ln15+16; tW2 rows o=ln15
            const bf16x8 w1a = *(const bf16x8*)(ws + WS_TW1 + m * 2048 + ln15 * 64 + kg * 16);
            const bf16x8 w1b = *(const bf16x8*)(ws + WS_TW1 + m * 2048 + 1024 + ln15 * 64 + kg * 16);
            const bf16x8 w2f = *(const bf16x8*)(ws + WS_TW2 + m * 1024 + ln15 * 64 + kg * 16);
            const float4 bq0 = *(const float4*)(s_tb1 + m * 32 + kg * 4);
            const float4 bq1 = *(const float4*)(s_tb1 + m * 32 + 16 + kg * 4);

            // MFMA1: C[h][b] = W1 x md  (bias tb1[h] as C-in; h = kg*4+r)
            f32x4 c0 = {bq0.x, bq0.y, bq0.z, bq0.w};
            f32x4 c1 = {bq1.x, bq1.y, bq1.z, bq1.w};
            c0 = __builtin_amdgcn_mfma_f32_16x16x32_bf16(w1a, af.v8, c0, 0, 0, 0);
            c1 = __builtin_amdgcn_mfma_f32_16x16x32_bf16(w1b, af.v8, c1, 0, 0, 0);

            // relu + pack pairs (h even/odd) to bf16
            #pragma unroll
            for (int r = 0; r < 4; ++r) { c0[r] = fmaxf(c0[r], 0.f); c1[r] = fmaxf(c1[r], 0.f); }
            unsigned int q00 = pkbf(c0[0], c0[1]), q01 = pkbf(c0[2], c0[3]);
            unsigned int q10 = pkbf(c1[0], c1[1]), q11 = pkbf(c1[2], c1[3]);

            // shfl-transpose: dest(b=ln15,kg) needs th pairs h=8kg..8kg+7
            unsigned int e0 = (unsigned int)__shfl((int)q00, sA, 64);
            unsigned int e1 = (unsigned int)__shfl((int)q10, sA, 64);
            unsigned int f0 = (unsigned int)__shfl((int)q01, sA, 64);
            unsigned int f1 = (unsigned int)__shfl((int)q11, sA, 64);
            unsigned int g0 = (unsigned int)__shfl((int)q00, sB, 64);
            unsigned int g1 = (unsigned int)__shfl((int)q10, sB, 64);
            unsigned int h0 = (unsigned int)__shfl((int)q01, sB, 64);
            unsigned int h1 = (unsigned int)__shfl((int)q11, sB, 64);
            union { unsigned int ui[4]; bf16x8 v8; } bfr;
            bfr.ui[0] = klow ? e0 : e1;
            bfr.ui[1] = klow ? f0 : f1;
            bfr.ui[2] = klow ? g0 : g1;
            bfr.ui[3] = klow ? h0 : h1;

            // MFMA2: acc[o][b] += tW2[o][h] x th[h][b]
            acc = __builtin_amdgcn_mfma_f32_16x16x32_bf16(w2f, bfr.v8, acc, 0, 0, 0);
        }

        // per-wave partials: acc row o=kg*4+r, col b=ln15 (b<8 real)
        {
            float* red = (float*)(smem + REDOFF + wave * REDSTR);
            if (ln15 < 8) {
                #pragma unroll
                for (int r = 0; r < 4; ++r) {
                    int o = kg * 4 + r;
                    if (o < OUT_W) red[o * 8 + ln15] = acc[r];
                }
            }
        }
        // cvt + write next tile into the other buffer (idle this phase)
        if (ti < 7) {
            char* bp = smem + (1 - cur) * BUFB + srow * ROWB + shalf * 4096;
            #pragma unroll
            for (int j = 0; j < 4; ++j) {
                uint4 pk;
                pk.x = pkbf(v[2 * j].x,     v[2 * j].y);
                pk.y = pkbf(v[2 * j].z,     v[2 * j].w);
                pk.z = pkbf(v[2 * j + 1].x, v[2 * j + 1].y);
                pk.w = pkbf(v[2 * j + 1].z, v[2 * j + 1].w);
                *(uint4*)(bp + j * 1024 + lane * 16) = pk;
            }
        }
        __syncthreads();

        // reduce 16 waves + tb2 + mean, write out
        if (tid < 80) {
            const int o = tid >> 3, b = tid & 7;
            float s = tb2s[o];
            #pragma unroll
            for (int w = 0; w < 16; ++w)
                s += *(const float*)(smem + REDOFF + w * REDSTR + (o * 8 + b) * 4);
            out[(size_t)((tile0 + ti) * 8 + b) * OUT_W + o] = s * 0.01f;
        }
        __syncthreads();   // red reads done before next tile's stores
    }
}

extern "C" void kernel_launch(void* const* d_in, const int* in_sizes, int n_in,
                              void* d_out, int out_size, void* d_ws, size_t ws_size,
                              hipStream_t stream) {
    const float* data = (const float*)d_in[0];
    const int*   idx  = (const int*)d_in[1];
    const float* Wi = (const float*)d_in[2];
    const float* bi = (const float*)d_in[3];
    const float* W1 = (const float*)d_in[4];
    const float* b1 = (const float*)d_in[5];
    const float* W2 = (const float*)d_in[6];
    const float* b2 = (const float*)d_in[7];
    const float* Wo = (const float*)d_in[8];
    const float* bo = (const float*)d_in[9];
    float* out = (float*)d_out;
    char* ws = (char*)d_ws;

    (void)hipFuncSetAttribute((const void*)main_kernel,
                              hipFuncAttributeMaxDynamicSharedMemorySize, LDS_SZ);

    hipLaunchKernelGGL(hyper_kernel, dim3(M_N), dim3(512), 0, stream,
                       idx, Wi, bi, W1, b1, W2, b2, Wo, bo, ws);
    hipLaunchKernelGGL(main_kernel, dim3(256), dim3(1024), LDS_SZ, stream,
                       data, ws, out);
}

// Round 4
// 99.787 us; speedup vs baseline: 1.1856x; 1.1856x over previous
//
#include <hip/hip_runtime.h>
#include <hip/hip_bf16.h>

typedef __attribute__((ext_vector_type(8))) short bf16x8;
typedef __attribute__((ext_vector_type(4))) float f32x4;

#define B_N   16384
#define INP_N 4096
#define M_N   100
#define K_N   32
#define HID_N 32
#define OUT_W 10

// ---------------- workspace layout (bytes) ----------------
#define WS_TW1 0u         // bf16[100][32][32]   tW1[m][h][k]      204800
#define WS_TW2 204800u    // bf16[100][16][32]   tW2[m][o(pad)][h] 102400
#define WS_TB1 307200u    // f32 [100][32]       tb1               12800
#define WS_TB2 320000u    // f32 [100][16]       tb2               6400
#define WS_COL 326400u    // u16 [100][32]       idx cols packed   6400
// total 332800 B

// ---------------- kernel-2 LDS layout (bytes) ----------------
#define ROWB   8208                  // bf16 row: 8192 B data + 16 B pad (4-bank rotate/row)
#define BUFB   (16 * ROWB)           // 131328: ONE 16-row tile buffer
#define REDOFF BUFB                  // per-wave out partials
#define REDSTR 656                   // 164 dwords (16B aligned, rotates 4 banks/wave)
#define COLOFF (REDOFF + 16 * REDSTR)   // 141824: u16[100][32] col table
#define TB1OFF (COLOFF + 6400)          // 148224: f32[100][32] tb1
#define TB2OFF (TB1OFF + 12800)         // 161024: f32[10] summed tb2
#define LDS_SZ (TB2OFF + 64)            // 161088  (<= 163840)

__device__ __forceinline__ unsigned int pkbf(float a, float b) {
    __hip_bfloat162 h2 = __float22bfloat162_rn(make_float2(a, b));
    unsigned int r;
    __builtin_memcpy(&r, &h2, 4);
    return r;
}

// =====================================================================
// Kernel 1: fused hypernetwork.  One block per m, 512 threads.
// (unchanged from round 3 for attribution)
// =====================================================================
__global__ __launch_bounds__(512) void hyper_kernel(
    const int* __restrict__ idx,
    const float* __restrict__ Wi, const float* __restrict__ bi,
    const float* __restrict__ W1, const float* __restrict__ b1,
    const float* __restrict__ W2, const float* __restrict__ b2,
    const float* __restrict__ Wo, const float* __restrict__ bo,
    char* __restrict__ ws)
{
    __shared__ int   s_idx[K_N];
    __shared__ float s_h0[64];
    __shared__ float s_h1[256];
    __shared__ float s_h2[128];
    const int m = blockIdx.x;
    const int t = threadIdx.x;

    __hip_bfloat16* tW1bf = (__hip_bfloat16*)(ws + WS_TW1);
    __hip_bfloat16* tW2bf = (__hip_bfloat16*)(ws + WS_TW2);
    float* tb1f = (float*)(ws + WS_TB1);
    float* tb2f = (float*)(ws + WS_TB2);
    unsigned short* colb = (unsigned short*)(ws + WS_COL);

    if (t < K_N) {
        int c = idx[m * K_N + t];
        s_idx[t] = c;
        colb[m * K_N + t] = (unsigned short)c;
    }
    __syncthreads();

    if (t < 64) {
        float s = bi[t];
        const float* wr = Wi + t * INP_N;
        int prev = -1;
        for (int k = 0; k < K_N; ++k) {
            int c = s_idx[k];
            if (c != prev) s += wr[c];
            prev = c;
        }
        s_h0[t] = fmaxf(s, 0.f);
    }
    __syncthreads();

    if (t < 256) {
        float4 a = {0.f, 0.f, 0.f, 0.f};
        const float4* wr = (const float4*)(W1 + t * 64);
        const float4* h0v = (const float4*)s_h0;
        #pragma unroll
        for (int i = 0; i < 16; ++i) {
            float4 w4 = wr[i], a4 = h0v[i];
            a.x += w4.x * a4.x; a.y += w4.y * a4.y;
            a.z += w4.z * a4.z; a.w += w4.w * a4.w;
        }
        s_h1[t] = fmaxf(b1[t] + (a.x + a.y) + (a.z + a.w), 0.f);
    }
    __syncthreads();

    if (t < 128) {
        float4 a = {0.f, 0.f, 0.f, 0.f};
        const float4* wr = (const float4*)(W2 + t * 256);
        const float4* h1v = (const float4*)s_h1;
        #pragma unroll
        for (int i = 0; i < 64; ++i) {
            float4 w4 = wr[i], a4 = h1v[i];
            a.x += w4.x * a4.x; a.y += w4.y * a4.y;
            a.z += w4.z * a4.z; a.w += w4.w * a4.w;
        }
        s_h2[t] = fmaxf(b2[t] + (a.x + a.y) + (a.z + a.w), 0.f);
    }
    __syncthreads();

    for (int o = t; o < 1386; o += 512) {
        float4 a = {0.f, 0.f, 0.f, 0.f};
        const float4* wr = (const float4*)(Wo + o * 128);
        const float4* h2v = (const float4*)s_h2;
        #pragma unroll
        for (int i = 0; i < 32; ++i) {
            float4 w4 = wr[i], a4 = h2v[i];
            a.x += w4.x * a4.x; a.y += w4.y * a4.y;
            a.z += w4.z * a4.z; a.w += w4.w * a4.w;
        }
        float s = bo[o] + (a.x + a.y) + (a.z + a.w);
        if (o < 1024) {
            tW1bf[m * 1024 + o] = __float2bfloat16(s);
        } else if (o < 1056) {
            tb1f[m * 32 + (o - 1024)] = s;
        } else if (o < 1376) {
            tW2bf[m * 512 + (o - 1056)] = __float2bfloat16(s);
        } else {
            tb2f[m * 16 + (o - 1376)] = s;
        }
    }
    if (t < 192) tW2bf[m * 512 + 320 + t] = __float2bfloat16(0.f);
}

// =====================================================================
// Kernel 2: main loop.  256 blocks (1/CU) x 1024 thr (16 waves).
// 16-row tiles (ALL 16 MFMA b-lanes real) -> 4 tiles/block, 400
// m-iterations/block (was 800).  Single 131KB buffer; next tile's
// half0 prefetched into regs during compute, half1 loaded in the
// write phase (bandwidth-bound, 16-wave TLP covers latency).
// =====================================================================
__global__ __launch_bounds__(1024) void main_kernel(
    const float* __restrict__ data,
    const char* __restrict__ ws,
    float* __restrict__ out)
{
    extern __shared__ char smem[];
    const int tid  = threadIdx.x;
    const int lane = tid & 63;
    const int wave = tid >> 6;       // 0..15 ; wave w stages row w of each tile
    const int kg   = lane >> 4;      // 0..3  (MFMA k-group)
    const int ln15 = lane & 15;

    unsigned int* s_col = (unsigned int*)(smem + COLOFF);
    float* s_tb1 = (float*)(smem + TB1OFF);
    float* tb2s  = (float*)(smem + TB2OFF);

    // ---- small tables -> LDS ----
    {
        const unsigned int* colg = (const unsigned int*)(ws + WS_COL);
        for (int i = tid; i < 1600; i += 1024) s_col[i] = colg[i];
        const float* tb1g = (const float*)(ws + WS_TB1);
        for (int i = tid; i < 3200; i += 1024) s_tb1[i] = tb1g[i];
        if (tid < OUT_W) {
            const float* tb2f = (const float*)(ws + WS_TB2);
            float s = 0.f;
            for (int mm = 0; mm < M_N; ++mm) s += tb2f[mm * 16 + tid];
            tb2s[tid] = s;
        }
    }

    const int row0 = blockIdx.x * 64;         // 4 tiles x 16 rows
    const int mlo = (wave * M_N) >> 4;
    const int mhi = ((wave + 1) * M_N) >> 4;
    const int sA = ln15 + ((kg & 1) << 5);    // shfl-transpose source lanes
    const int sB = sA + 16;
    const bool klow = (kg < 2);

    float4 v[8];                              // staging regs (one half-row)

    // ---- prologue: stage tile0 fully (both halves) ----
    {
        const float* rp = data + (size_t)(row0 + wave) * INP_N;
        char* bp = smem + wave * ROWB;
        #pragma unroll
        for (int half = 0; half < 2; ++half) {
            #pragma unroll
            for (int j = 0; j < 4; ++j) {
                v[2 * j]     = *(const float4*)(rp + half * 2048 + j * 512 + lane * 8);
                v[2 * j + 1] = *(const float4*)(rp + half * 2048 + j * 512 + lane * 8 + 4);
            }
            #pragma unroll
            for (int j = 0; j < 4; ++j) {
                uint4 pk;
                pk.x = pkbf(v[2 * j].x,     v[2 * j].y);
                pk.y = pkbf(v[2 * j].z,     v[2 * j].w);
                pk.z = pkbf(v[2 * j + 1].x, v[2 * j + 1].y);
                pk.w = pkbf(v[2 * j + 1].z, v[2 * j + 1].w);
                *(uint4*)(bp + half * 4096 + j * 1024 + lane * 16) = pk;
            }
        }
    }
    __syncthreads();

    for (int ti = 0; ti < 4; ++ti) {
        // early-issue next tile half0 (HBM hides under m-loop)
        if (ti < 3) {
            const float* rp = data + (size_t)(row0 + (ti + 1) * 16 + wave) * INP_N;
            #pragma unroll
            for (int j = 0; j < 4; ++j) {
                v[2 * j]     = *(const float4*)(rp + j * 512 + lane * 8);
                v[2 * j + 1] = *(const float4*)(rp + j * 512 + lane * 8 + 4);
            }
        }

        // ---- m-loop on current tile (16 real rows) ----
        const char* gbase = smem + ln15 * ROWB;
        f32x4 acc = {0.f, 0.f, 0.f, 0.f};

        for (int m = mlo; m < mhi; ++m) {
            // B-frag (md): md[b=ln15][k=kg*8+j] gathered from staged bf16 row
            const uint4 cw = *(const uint4*)((const char*)s_col + m * 64 + kg * 16);
            unsigned short u0 = *(const unsigned short*)(gbase + 2 * (cw.x & 0xFFFFu));
            unsigned short u1 = *(const unsigned short*)(gbase + 2 * (cw.x >> 16));
            unsigned short u2 = *(const unsigned short*)(gbase + 2 * (cw.y & 0xFFFFu));
            unsigned short u3 = *(const unsigned short*)(gbase + 2 * (cw.y >> 16));
            unsigned short u4 = *(const unsigned short*)(gbase + 2 * (cw.z & 0xFFFFu));
            unsigned short u5 = *(const unsigned short*)(gbase + 2 * (cw.z >> 16));
            unsigned short u6 = *(const unsigned short*)(gbase + 2 * (cw.w & 0xFFFFu));
            unsigned short u7 = *(const unsigned short*)(gbase + 2 * (cw.w >> 16));
            union { unsigned int ui[4]; bf16x8 v8; } af;
            af.ui[0] = (unsigned int)u0 | ((unsigned int)u1 << 16);
            af.ui[1] = (unsigned int)u2 | ((unsigned int)u3 << 16);
            af.ui[2] = (unsigned int)u4 | ((unsigned int)u5 << 16);
            af.ui[3] = (unsigned int)u6 | ((unsigned int)u7 << 16);

            // A-frags: tW1 rows h=ln15 / h=ln15+16; tW2 rows o=ln15
            const bf16x8 w1a = *(const bf16x8*)(ws + WS_TW1 + m * 2048 + ln15 * 64 + kg * 16);
            const bf16x8 w1b = *(const bf16x8*)(ws + WS_TW1 + m * 2048 + 1024 + ln15 * 64 + kg * 16);
            const bf16x8 w2f = *(const bf16x8*)(ws + WS_TW2 + m * 1024 + ln15 * 64 + kg * 16);
            const float4 bq0 = *(const float4*)(s_tb1 + m * 32 + kg * 4);
            const float4 bq1 = *(const float4*)(s_tb1 + m * 32 + 16 + kg * 4);

            // MFMA1: C[h][b] = W1 x md  (bias tb1[h] as C-in; h = kg*4+r)
            f32x4 c0 = {bq0.x, bq0.y, bq0.z, bq0.w};
            f32x4 c1 = {bq1.x, bq1.y, bq1.z, bq1.w};
            c0 = __builtin_amdgcn_mfma_f32_16x16x32_bf16(w1a, af.v8, c0, 0, 0, 0);
            c1 = __builtin_amdgcn_mfma_f32_16x16x32_bf16(w1b, af.v8, c1, 0, 0, 0);

            // relu + pack pairs (h even/odd) to bf16
            #pragma unroll
            for (int r = 0; r < 4; ++r) { c0[r] = fmaxf(c0[r], 0.f); c1[r] = fmaxf(c1[r], 0.f); }
            unsigned int q00 = pkbf(c0[0], c0[1]), q01 = pkbf(c0[2], c0[3]);
            unsigned int q10 = pkbf(c1[0], c1[1]), q11 = pkbf(c1[2], c1[3]);

            // shfl-transpose: dest(b=ln15,kg) needs th pairs h=8kg..8kg+7
            unsigned int e0 = (unsigned int)__shfl((int)q00, sA, 64);
            unsigned int e1 = (unsigned int)__shfl((int)q10, sA, 64);
            unsigned int f0 = (unsigned int)__shfl((int)q01, sA, 64);
            unsigned int f1 = (unsigned int)__shfl((int)q11, sA, 64);
            unsigned int g0 = (unsigned int)__shfl((int)q00, sB, 64);
            unsigned int g1 = (unsigned int)__shfl((int)q10, sB, 64);
            unsigned int h0 = (unsigned int)__shfl((int)q01, sB, 64);
            unsigned int h1 = (unsigned int)__shfl((int)q11, sB, 64);
            union { unsigned int ui[4]; bf16x8 v8; } bfr;
            bfr.ui[0] = klow ? e0 : e1;
            bfr.ui[1] = klow ? f0 : f1;
            bfr.ui[2] = klow ? g0 : g1;
            bfr.ui[3] = klow ? h0 : h1;

            // MFMA2: acc[o][b] += tW2[o][h] x th[h][b]
            acc = __builtin_amdgcn_mfma_f32_16x16x32_bf16(w2f, bfr.v8, acc, 0, 0, 0);
        }

        // per-wave partials: acc row o=kg*4+r, col b=ln15 (all 16 b real)
        {
            float* red = (float*)(smem + REDOFF + wave * REDSTR);
            #pragma unroll
            for (int r = 0; r < 4; ++r) {
                int o = kg * 4 + r;
                if (o < OUT_W) red[o * 16 + ln15] = acc[r];
            }
        }
        __syncthreads();

        // reduce 16 waves + tb2 + mean, write out (160 threads)
        if (tid < 160) {
            const int o = tid >> 4, b = tid & 15;
            float s = tb2s[o];
            #pragma unroll
            for (int w = 0; w < 16; ++w)
                s += *(const float*)(smem + REDOFF + w * REDSTR + tid * 4);
            out[(size_t)(row0 + ti * 16 + b) * OUT_W + o] = s * 0.01f;
        }

        // write phase: half0 from regs, then load+write half1
        if (ti < 3) {
            char* bp = smem + wave * ROWB;
            #pragma unroll
            for (int j = 0; j < 4; ++j) {
                uint4 pk;
                pk.x = pkbf(v[2 * j].x,     v[2 * j].y);
                pk.y = pkbf(v[2 * j].z,     v[2 * j].w);
                pk.z = pkbf(v[2 * j + 1].x, v[2 * j + 1].y);
                pk.w = pkbf(v[2 * j + 1].z, v[2 * j + 1].w);
                *(uint4*)(bp + j * 1024 + lane * 16) = pk;
            }
            const float* rp = data + (size_t)(row0 + (ti + 1) * 16 + wave) * INP_N + 2048;
            #pragma unroll
            for (int j = 0; j < 4; ++j) {
                v[2 * j]     = *(const float4*)(rp + j * 512 + lane * 8);
                v[2 * j + 1] = *(const float4*)(rp + j * 512 + lane * 8 + 4);
            }
            #pragma unroll
            for (int j = 0; j < 4; ++j) {
                uint4 pk;
                pk.x = pkbf(v[2 * j].x,     v[2 * j].y);
                pk.y = pkbf(v[2 * j].z,     v[2 * j].w);
                pk.z = pkbf(v[2 * j + 1].x, v[2 * j + 1].y);
                pk.w = pkbf(v[2 * j + 1].z, v[2 * j + 1].w);
                *(uint4*)(bp + 4096 + j * 1024 + lane * 16) = pk;
            }
        }
        __syncthreads();
    }
}

extern "C" void kernel_launch(void* const* d_in, const int* in_sizes, int n_in,
                              void* d_out, int out_size, void* d_ws, size_t ws_size,
                              hipStream_t stream) {
    const float* data = (const float*)d_in[0];
    const int*   idx  = (const int*)d_in[1];
    const float* Wi = (const float*)d_in[2];
    const float* bi = (const float*)d_in[3];
    const float* W1 = (const float*)d_in[4];
    const float* b1 = (const float*)d_in[5];
    const float* W2 = (const float*)d_in[6];
    const float* b2 = (const float*)d_in[7];
    const float* Wo = (const float*)d_in[8];
    const float* bo = (const float*)d_in[9];
    float* out = (float*)d_out;
    char* ws = (char*)d_ws;

    (void)hipFuncSetAttribute((const void*)main_kernel,
                              hipFuncAttributeMaxDynamicSharedMemorySize, LDS_SZ);

    hipLaunchKernelGGL(hyper_kernel, dim3(M_N), dim3(512), 0, stream,
                       idx, Wi, bi, W1, b1, W2, b2, Wo, bo, ws);
    hipLaunchKernelGGL(main_kernel, dim3(256), dim3(1024), LDS_SZ, stream,
                       data, ws, out);
}

// Round 5
// 97.978 us; speedup vs baseline: 1.2075x; 1.0185x over previous
//
#include <hip/hip_runtime.h>
#include <hip/hip_bf16.h>

typedef __attribute__((ext_vector_type(8))) short bf16x8;
typedef __attribute__((ext_vector_type(4))) float f32x4;

#define B_N   16384
#define INP_N 4096
#define M_N   100
#define K_N   32
#define HID_N 32
#define OUT_W 10

// ---------------- workspace layout (bytes) ----------------
#define WS_TW1 0u         // bf16[100][32][32]   tW1[m][h][k]      204800
#define WS_TW2 204800u    // bf16[100][16][32]   tW2[m][o(pad)][k-slot] 102400
#define WS_TB1 307200u    // f32 [100][32]       tb1               12800
#define WS_TB2 320000u    // f32 [100][16]       tb2               6400
#define WS_COL 326400u    // u16 [100][32]       idx cols packed   6400
// total 332800 B

// ---------------- kernel-2 LDS layout (bytes) ----------------
#define ROWB   8208                  // bf16 row: 8192 B data + 16 B pad (4-bank rotate/row)
#define BUFB   (16 * ROWB)           // 131328: ONE 16-row tile buffer
#define REDOFF BUFB                  // per-wave out partials
#define REDSTR 656                   // 164 dwords (16B aligned, rotates 4 banks/wave)
#define COLOFF (REDOFF + 16 * REDSTR)   // 141824: u16[100][32] col table
#define TB1OFF (COLOFF + 6400)          // 148224: f32[100][32] tb1
#define TB2OFF (TB1OFF + 12800)         // 161024: f32[10] summed tb2
#define LDS_SZ (TB2OFF + 64)            // 161088  (<= 163840)

__device__ __forceinline__ unsigned int pkbf(float a, float b) {
    __hip_bfloat162 h2 = __float22bfloat162_rn(make_float2(a, b));
    unsigned int r;
    __builtin_memcpy(&r, &h2, 4);
    return r;
}

// =====================================================================
// Kernel 1: fused hypernetwork.  One block per m, 512 threads.
// Identical to round 4 EXCEPT tW2 is written in MFMA k-slot-permuted
// order: slot(h) = ((h&15)>>2)*8 + (h&3) + (h>=16 ? 4 : 0), so that
// main_kernel's MFMA2 B-frag needs NO cross-lane shuffle.
// =====================================================================
__global__ __launch_bounds__(512) void hyper_kernel(
    const int* __restrict__ idx,
    const float* __restrict__ Wi, const float* __restrict__ bi,
    const float* __restrict__ W1, const float* __restrict__ b1,
    const float* __restrict__ W2, const float* __restrict__ b2,
    const float* __restrict__ Wo, const float* __restrict__ bo,
    char* __restrict__ ws)
{
    __shared__ int   s_idx[K_N];
    __shared__ float s_h0[64];
    __shared__ float s_h1[256];
    __shared__ float s_h2[128];
    const int m = blockIdx.x;
    const int t = threadIdx.x;

    __hip_bfloat16* tW1bf = (__hip_bfloat16*)(ws + WS_TW1);
    __hip_bfloat16* tW2bf = (__hip_bfloat16*)(ws + WS_TW2);
    float* tb1f = (float*)(ws + WS_TB1);
    float* tb2f = (float*)(ws + WS_TB2);
    unsigned short* colb = (unsigned short*)(ws + WS_COL);

    if (t < K_N) {
        int c = idx[m * K_N + t];
        s_idx[t] = c;
        colb[m * K_N + t] = (unsigned short)c;
    }
    __syncthreads();

    if (t < 64) {
        float s = bi[t];
        const float* wr = Wi + t * INP_N;
        int prev = -1;
        for (int k = 0; k < K_N; ++k) {
            int c = s_idx[k];
            if (c != prev) s += wr[c];
            prev = c;
        }
        s_h0[t] = fmaxf(s, 0.f);
    }
    __syncthreads();

    if (t < 256) {
        float4 a = {0.f, 0.f, 0.f, 0.f};
        const float4* wr = (const float4*)(W1 + t * 64);
        const float4* h0v = (const float4*)s_h0;
        #pragma unroll
        for (int i = 0; i < 16; ++i) {
            float4 w4 = wr[i], a4 = h0v[i];
            a.x += w4.x * a4.x; a.y += w4.y * a4.y;
            a.z += w4.z * a4.z; a.w += w4.w * a4.w;
        }
        s_h1[t] = fmaxf(b1[t] + (a.x + a.y) + (a.z + a.w), 0.f);
    }
    __syncthreads();

    if (t < 128) {
        float4 a = {0.f, 0.f, 0.f, 0.f};
        const float4* wr = (const float4*)(W2 + t * 256);
        const float4* h1v = (const float4*)s_h1;
        #pragma unroll
        for (int i = 0; i < 64; ++i) {
            float4 w4 = wr[i], a4 = h1v[i];
            a.x += w4.x * a4.x; a.y += w4.y * a4.y;
            a.z += w4.z * a4.z; a.w += w4.w * a4.w;
        }
        s_h2[t] = fmaxf(b2[t] + (a.x + a.y) + (a.z + a.w), 0.f);
    }
    __syncthreads();

    for (int o = t; o < 1386; o += 512) {
        float4 a = {0.f, 0.f, 0.f, 0.f};
        const float4* wr = (const float4*)(Wo + o * 128);
        const float4* h2v = (const float4*)s_h2;
        #pragma unroll
        for (int i = 0; i < 32; ++i) {
            float4 w4 = wr[i], a4 = h2v[i];
            a.x += w4.x * a4.x; a.y += w4.y * a4.y;
            a.z += w4.z * a4.z; a.w += w4.w * a4.w;
        }
        float s = bo[o] + (a.x + a.y) + (a.z + a.w);
        if (o < 1024) {
            tW1bf[m * 1024 + o] = __float2bfloat16(s);
        } else if (o < 1056) {
            tb1f[m * 32 + (o - 1024)] = s;
        } else if (o < 1376) {
            // k-slot permuted store (see main_kernel MFMA2)
            int i2 = o - 1056;
            int oo = i2 >> 5, h = i2 & 31;
            int sl = (((h & 15) >> 2) << 3) + (h & 3) + ((h >> 4) << 2);
            tW2bf[m * 512 + oo * 32 + sl] = __float2bfloat16(s);
        } else {
            tb2f[m * 16 + (o - 1376)] = s;
        }
    }
    if (t < 192) tW2bf[m * 512 + 320 + t] = __float2bfloat16(0.f);
}

// =====================================================================
// Kernel 2: main loop.  256 blocks (1/CU) x 1024 thr (16 waves).
// 16-row tiles, 400 m-iters/block.  MFMA2's B-frag is now built
// DIRECTLY from MFMA1's relu'd output (tW2 k-slot permutation) --
// zero cross-lane ops.  Column word cw prefetched one m ahead.
// =====================================================================
__global__ __launch_bounds__(1024) void main_kernel(
    const float* __restrict__ data,
    const char* __restrict__ ws,
    float* __restrict__ out)
{
    extern __shared__ char smem[];
    const int tid  = threadIdx.x;
    const int lane = tid & 63;
    const int wave = tid >> 6;       // 0..15 ; wave w stages row w of each tile
    const int kg   = lane >> 4;      // 0..3  (MFMA k-group)
    const int ln15 = lane & 15;

    unsigned int* s_col = (unsigned int*)(smem + COLOFF);
    float* s_tb1 = (float*)(smem + TB1OFF);
    float* tb2s  = (float*)(smem + TB2OFF);

    // ---- small tables -> LDS ----
    {
        const unsigned int* colg = (const unsigned int*)(ws + WS_COL);
        for (int i = tid; i < 1600; i += 1024) s_col[i] = colg[i];
        const float* tb1g = (const float*)(ws + WS_TB1);
        for (int i = tid; i < 3200; i += 1024) s_tb1[i] = tb1g[i];
        if (tid < OUT_W) {
            const float* tb2f = (const float*)(ws + WS_TB2);
            float s = 0.f;
            for (int mm = 0; mm < M_N; ++mm) s += tb2f[mm * 16 + tid];
            tb2s[tid] = s;
        }
    }

    const int row0 = blockIdx.x * 64;         // 4 tiles x 16 rows
    const int mlo = (wave * M_N) >> 4;
    const int mhi = ((wave + 1) * M_N) >> 4;

    float4 v[8];                              // staging regs (one half-row)

    // ---- prologue: stage tile0 fully (both halves) ----
    {
        const float* rp = data + (size_t)(row0 + wave) * INP_N;
        char* bp = smem + wave * ROWB;
        #pragma unroll
        for (int half = 0; half < 2; ++half) {
            #pragma unroll
            for (int j = 0; j < 4; ++j) {
                v[2 * j]     = *(const float4*)(rp + half * 2048 + j * 512 + lane * 8);
                v[2 * j + 1] = *(const float4*)(rp + half * 2048 + j * 512 + lane * 8 + 4);
            }
            #pragma unroll
            for (int j = 0; j < 4; ++j) {
                uint4 pk;
                pk.x = pkbf(v[2 * j].x,     v[2 * j].y);
                pk.y = pkbf(v[2 * j].z,     v[2 * j].w);
                pk.z = pkbf(v[2 * j + 1].x, v[2 * j + 1].y);
                pk.w = pkbf(v[2 * j + 1].z, v[2 * j + 1].w);
                *(uint4*)(bp + half * 4096 + j * 1024 + lane * 16) = pk;
            }
        }
    }
    __syncthreads();

    for (int ti = 0; ti < 4; ++ti) {
        // early-issue next tile half0 (HBM hides under m-loop)
        if (ti < 3) {
            const float* rp = data + (size_t)(row0 + (ti + 1) * 16 + wave) * INP_N;
            #pragma unroll
            for (int j = 0; j < 4; ++j) {
                v[2 * j]     = *(const float4*)(rp + j * 512 + lane * 8);
                v[2 * j + 1] = *(const float4*)(rp + j * 512 + lane * 8 + 4);
            }
        }

        // ---- m-loop on current tile (16 real rows) ----
        const char* gbase = smem + ln15 * ROWB;
        f32x4 acc = {0.f, 0.f, 0.f, 0.f};

        // prefetch first column word
        uint4 cw = *(const uint4*)((const char*)s_col + mlo * 64 + kg * 16);

        for (int m = mlo; m < mhi; ++m) {
            // prefetch next m's column word (dep chain head)
            const int mn = (m + 1 < M_N) ? (m + 1) : m;
            const uint4 cwn = *(const uint4*)((const char*)s_col + mn * 64 + kg * 16);

            // B-frag (md): md[b=ln15][k=kg*8+j] gathered from staged bf16 row
            unsigned short u0 = *(const unsigned short*)(gbase + 2 * (cw.x & 0xFFFFu));
            unsigned short u1 = *(const unsigned short*)(gbase + 2 * (cw.x >> 16));
            unsigned short u2 = *(const unsigned short*)(gbase + 2 * (cw.y & 0xFFFFu));
            unsigned short u3 = *(const unsigned short*)(gbase + 2 * (cw.y >> 16));
            unsigned short u4 = *(const unsigned short*)(gbase + 2 * (cw.z & 0xFFFFu));
            unsigned short u5 = *(const unsigned short*)(gbase + 2 * (cw.z >> 16));
            unsigned short u6 = *(const unsigned short*)(gbase + 2 * (cw.w & 0xFFFFu));
            unsigned short u7 = *(const unsigned short*)(gbase + 2 * (cw.w >> 16));
            union { unsigned int ui[4]; bf16x8 v8; } af;
            af.ui[0] = (unsigned int)u0 | ((unsigned int)u1 << 16);
            af.ui[1] = (unsigned int)u2 | ((unsigned int)u3 << 16);
            af.ui[2] = (unsigned int)u4 | ((unsigned int)u5 << 16);
            af.ui[3] = (unsigned int)u6 | ((unsigned int)u7 << 16);

            // A-frags: tW1 rows h=ln15 / h=ln15+16; tW2 rows o=ln15 (slot-permuted)
            const bf16x8 w1a = *(const bf16x8*)(ws + WS_TW1 + m * 2048 + ln15 * 64 + kg * 16);
            const bf16x8 w1b = *(const bf16x8*)(ws + WS_TW1 + m * 2048 + 1024 + ln15 * 64 + kg * 16);
            const bf16x8 w2f = *(const bf16x8*)(ws + WS_TW2 + m * 1024 + ln15 * 64 + kg * 16);
            const float4 bq0 = *(const float4*)(s_tb1 + m * 32 + kg * 4);
            const float4 bq1 = *(const float4*)(s_tb1 + m * 32 + 16 + kg * 4);

            // MFMA1: C[h][b] = W1 x md  (bias tb1[h] as C-in; h = kg*4+r)
            f32x4 c0 = {bq0.x, bq0.y, bq0.z, bq0.w};
            f32x4 c1 = {bq1.x, bq1.y, bq1.z, bq1.w};
            c0 = __builtin_amdgcn_mfma_f32_16x16x32_bf16(w1a, af.v8, c0, 0, 0, 0);
            c1 = __builtin_amdgcn_mfma_f32_16x16x32_bf16(w1b, af.v8, c1, 0, 0, 0);

            // relu + pack: lane(b,kg) holds exactly its MFMA2 B-frag k-slots
            // (k=kg*8+j <-> h = 4kg + (j&3) + (j>=4 ? 16 : 0), matching tW2 store)
            #pragma unroll
            for (int r = 0; r < 4; ++r) { c0[r] = fmaxf(c0[r], 0.f); c1[r] = fmaxf(c1[r], 0.f); }
            union { unsigned int ui[4]; bf16x8 v8; } bfr;
            bfr.ui[0] = pkbf(c0[0], c0[1]);
            bfr.ui[1] = pkbf(c0[2], c0[3]);
            bfr.ui[2] = pkbf(c1[0], c1[1]);
            bfr.ui[3] = pkbf(c1[2], c1[3]);

            // MFMA2: acc[o][b] += tW2[o][.] x th[.][b]
            acc = __builtin_amdgcn_mfma_f32_16x16x32_bf16(w2f, bfr.v8, acc, 0, 0, 0);

            cw = cwn;
        }

        // per-wave partials: acc row o=kg*4+r, col b=ln15 (all 16 b real)
        {
            float* red = (float*)(smem + REDOFF + wave * REDSTR);
            #pragma unroll
            for (int r = 0; r < 4; ++r) {
                int o = kg * 4 + r;
                if (o < OUT_W) red[o * 16 + ln15] = acc[r];
            }
        }
        __syncthreads();

        // reduce 16 waves + tb2 + mean, write out (160 threads)
        if (tid < 160) {
            const int o = tid >> 4, b = tid & 15;
            float s = tb2s[o];
            #pragma unroll
            for (int w = 0; w < 16; ++w)
                s += *(const float*)(smem + REDOFF + w * REDSTR + tid * 4);
            out[(size_t)(row0 + ti * 16 + b) * OUT_W + o] = s * 0.01f;
        }

        // write phase: half0 from regs, then load+write half1
        if (ti < 3) {
            char* bp = smem + wave * ROWB;
            #pragma unroll
            for (int j = 0; j < 4; ++j) {
                uint4 pk;
                pk.x = pkbf(v[2 * j].x,     v[2 * j].y);
                pk.y = pkbf(v[2 * j].z,     v[2 * j].w);
                pk.z = pkbf(v[2 * j + 1].x, v[2 * j + 1].y);
                pk.w = pkbf(v[2 * j + 1].z, v[2 * j + 1].w);
                *(uint4*)(bp + j * 1024 + lane * 16) = pk;
            }
            const float* rp = data + (size_t)(row0 + (ti + 1) * 16 + wave) * INP_N + 2048;
            #pragma unroll
            for (int j = 0; j < 4; ++j) {
                v[2 * j]     = *(const float4*)(rp + j * 512 + lane * 8);
                v[2 * j + 1] = *(const float4*)(rp + j * 512 + lane * 8 + 4);
            }
            #pragma unroll
            for (int j = 0; j < 4; ++j) {
                uint4 pk;
                pk.x = pkbf(v[2 * j].x,     v[2 * j].y);
                pk.y = pkbf(v[2 * j].z,     v[2 * j].w);
                pk.z = pkbf(v[2 * j + 1].x, v[2 * j + 1].y);
                pk.w = pkbf(v[2 * j + 1].z, v[2 * j + 1].w);
                *(uint4*)(bp + 4096 + j * 1024 + lane * 16) = pk;
            }
        }
        __syncthreads();
    }
}

extern "C" void kernel_launch(void* const* d_in, const int* in_sizes, int n_in,
                              void* d_out, int out_size, void* d_ws, size_t ws_size,
                              hipStream_t stream) {
    const float* data = (const float*)d_in[0];
    const int*   idx  = (const int*)d_in[1];
    const float* Wi = (const float*)d_in[2];
    const float* bi = (const float*)d_in[3];
    const float* W1 = (const float*)d_in[4];
    const float* b1 = (const float*)d_in[5];
    const float* W2 = (const float*)d_in[6];
    const float* b2 = (const float*)d_in[7];
    const float* Wo = (const float*)d_in[8];
    const float* bo = (const float*)d_in[9];
    float* out = (float*)d_out;
    char* ws = (char*)d_ws;

    (void)hipFuncSetAttribute((const void*)main_kernel,
                              hipFuncAttributeMaxDynamicSharedMemorySize, LDS_SZ);

    hipLaunchKernelGGL(hyper_kernel, dim3(M_N), dim3(512), 0, stream,
                       idx, Wi, bi, W1, b1, W2, b2, Wo, bo, ws);
    hipLaunchKernelGGL(main_kernel, dim3(256), dim3(1024), LDS_SZ, stream,
                       data, ws, out);
}